// Round 1
// baseline (363.574 us; speedup 1.0000x reference)
//
#include <hip/hip_runtime.h>
#include <hip/hip_bf16.h>
#include <cstdint>
#include <cstddef>

typedef __bf16 bf16x8 __attribute__((ext_vector_type(8)));
typedef float  f32x4  __attribute__((ext_vector_type(4)));

__device__ __forceinline__ unsigned short f2bf(float f) {
    __hip_bfloat16 b = __float2bfloat16(f);
    return *reinterpret_cast<unsigned short*>(&b);
}

// ---------------- aux kernels ----------------

__global__ void zero2_kernel(float* p) {
    if (threadIdx.x < 2) p[threadIdx.x] = 0.0f;
}

__global__ void abs_sum_kernel(const float* __restrict__ w, int n, float* __restrict__ out) {
    float s = 0.0f;
    for (int i = blockIdx.x * blockDim.x + threadIdx.x; i < n; i += gridDim.x * blockDim.x)
        s += fabsf(w[i]);
    // wave reduce (64 lanes)
    #pragma unroll
    for (int o = 32; o > 0; o >>= 1) s += __shfl_down(s, o, 64);
    __shared__ float part[4];
    int lane = threadIdx.x & 63, wid = threadIdx.x >> 6;
    if (lane == 0) part[wid] = s;
    __syncthreads();
    if (threadIdx.x == 0) {
        atomicAdd(out, part[0] + part[1] + part[2] + part[3]);
    }
}

__global__ void ternarize_kernel(const float4* __restrict__ w, ushort4* __restrict__ wt,
                                 int n4, const float* __restrict__ sum, float inv_n) {
    float scale = fmaxf(*sum * inv_n, 1e-8f);
    float inv = 1.0f / scale;
    for (int i = blockIdx.x * blockDim.x + threadIdx.x; i < n4; i += gridDim.x * blockDim.x) {
        float4 v = w[i];
        ushort4 o;
        o.x = f2bf(fminf(fmaxf(rintf(v.x * inv), -1.0f), 1.0f));
        o.y = f2bf(fminf(fmaxf(rintf(v.y * inv), -1.0f), 1.0f));
        o.z = f2bf(fminf(fmaxf(rintf(v.z * inv), -1.0f), 1.0f));
        o.w = f2bf(fminf(fmaxf(rintf(v.w * inv), -1.0f), 1.0f));
        wt[i] = o;
    }
}

__global__ void cvt_bf16_kernel(const float4* __restrict__ in, ushort4* __restrict__ out, int n4) {
    for (int i = blockIdx.x * blockDim.x + threadIdx.x; i < n4; i += gridDim.x * blockDim.x) {
        float4 v = in[i];
        ushort4 o;
        o.x = f2bf(v.x); o.y = f2bf(v.y); o.z = f2bf(v.z); o.w = f2bf(v.w);
        out[i] = o;
    }
}

// ---------------- GEMM (NT: C[m][n] = sum_k A[m][k]*B[n][k]) ----------------
// BM=BN=128, BK=64; 256 threads = 4 waves, each wave 64x64 via 4x4 of 16x16x32 MFMA.
// EPI==0: C = bf16 h, epilogue bias+exact GELU.  EPI==1: C = fp32 out, epilogue bias.

template <int EPI>
__global__ __launch_bounds__(256)
void gemm_bt_kernel(const unsigned short* __restrict__ A,
                    const unsigned short* __restrict__ B,
                    const float* __restrict__ bias,
                    void* __restrict__ C,
                    int K, int N) {
    __shared__ __align__(16) unsigned short As[128 * 64];
    __shared__ __align__(16) unsigned short Bs[128 * 64];

    const int tid  = threadIdx.x;
    const int lane = tid & 63;
    const int wid  = tid >> 6;
    const int wr   = wid >> 1;      // wave row 0..1
    const int wc   = wid & 1;       // wave col 0..1
    const int mBase = wr * 64;
    const int nBase = wc * 64;
    const int lr = lane & 15;       // 0..15
    const int lq = lane >> 4;       // quad 0..3

    const size_t aRow0 = (size_t)blockIdx.y * 128;
    const size_t bRow0 = (size_t)blockIdx.x * 128;

    f32x4 acc[4][4];
    #pragma unroll
    for (int i = 0; i < 4; ++i)
        #pragma unroll
        for (int j = 0; j < 4; ++j)
            acc[i][j] = f32x4{0.f, 0.f, 0.f, 0.f};

    for (int k0 = 0; k0 < K; k0 += 64) {
        __syncthreads();
        // stage 128x64 bf16 A-tile and B-tile via global_load_lds (16B/lane)
        #pragma unroll
        for (int t = 0; t < 4; ++t) {
            int chunk = t * 256 + tid;          // 0..1023, 8 bf16 per chunk
            int r = chunk >> 3;                 // row in tile
            int c = (chunk & 7) << 3;           // col in tile
            const unsigned short* ga = A + (aRow0 + r) * (size_t)K + k0 + c;
            const unsigned short* gb = B + (bRow0 + r) * (size_t)K + k0 + c;
            __builtin_amdgcn_global_load_lds(
                (__attribute__((address_space(1))) void*)ga,
                (__attribute__((address_space(3))) void*)(&As[chunk * 8]), 16, 0, 0);
            __builtin_amdgcn_global_load_lds(
                (__attribute__((address_space(1))) void*)gb,
                (__attribute__((address_space(3))) void*)(&Bs[chunk * 8]), 16, 0, 0);
        }
        __syncthreads();
        // compute: 2 k-steps of 32
        #pragma unroll
        for (int ks = 0; ks < 2; ++ks) {
            bf16x8 avec[4], bvec[4];
            #pragma unroll
            for (int i = 0; i < 4; ++i) {
                avec[i] = *(const bf16x8*)&As[(mBase + i * 16 + lr) * 64 + ks * 32 + lq * 8];
                bvec[i] = *(const bf16x8*)&Bs[(nBase + i * 16 + lr) * 64 + ks * 32 + lq * 8];
            }
            #pragma unroll
            for (int mi = 0; mi < 4; ++mi)
                #pragma unroll
                for (int ni = 0; ni < 4; ++ni)
                    acc[mi][ni] = __builtin_amdgcn_mfma_f32_16x16x32_bf16(
                        avec[mi], bvec[ni], acc[mi][ni], 0, 0, 0);
        }
    }

    // epilogue. C/D layout: col = lane&15, row = (lane>>4)*4 + reg
    #pragma unroll
    for (int mi = 0; mi < 4; ++mi) {
        #pragma unroll
        for (int ni = 0; ni < 4; ++ni) {
            int col = (int)bRow0 + nBase + ni * 16 + lr;
            float bv = bias[col];
            #pragma unroll
            for (int r = 0; r < 4; ++r) {
                size_t row = aRow0 + mBase + mi * 16 + lq * 4 + r;
                float v = acc[mi][ni][r] + bv;
                if (EPI == 0) {
                    // exact GELU: 0.5*x*(1+erf(x/sqrt(2)))
                    v = 0.5f * v * (1.0f + erff(v * 0.70710678118f));
                    ((unsigned short*)C)[row * (size_t)N + col] = f2bf(v);
                } else {
                    ((float*)C)[row * (size_t)N + col] = v;
                }
            }
        }
    }
}

// ---------------- launch ----------------

extern "C" void kernel_launch(void* const* d_in, const int* in_sizes, int n_in,
                              void* d_out, int out_size, void* d_ws, size_t ws_size,
                              hipStream_t stream) {
    const float* x  = (const float*)d_in[0];   // [4,2048,1024] = 8388608
    const float* W1 = (const float*)d_in[1];   // [4096,1024]   = 4194304
    const float* b1 = (const float*)d_in[2];   // [4096]
    const float* W2 = (const float*)d_in[3];   // [1024,4096]   = 4194304
    const float* b2 = (const float*)d_in[4];   // [1024]
    float* out = (float*)d_out;                // fp32 [4,2048,1024]

    const int M = 8192, EMB = 1024, FF = 4096;
    const int nW = FF * EMB;                   // 4194304

    char* ws = (char*)d_ws;
    float* sums = (float*)ws;                                    // 2 floats
    unsigned short* W1t = (unsigned short*)(ws + 256);           // 8.39 MB
    unsigned short* W2t = W1t + (size_t)nW;                      // 8.39 MB
    unsigned short* xb  = W2t + (size_t)nW;                      // 16.78 MB
    unsigned short* h   = xb  + (size_t)M * EMB;                 // 67.1 MB

    zero2_kernel<<<1, 64, 0, stream>>>(sums);
    abs_sum_kernel<<<512, 256, 0, stream>>>(W1, nW, &sums[0]);
    abs_sum_kernel<<<512, 256, 0, stream>>>(W2, nW, &sums[1]);
    ternarize_kernel<<<1024, 256, 0, stream>>>((const float4*)W1, (ushort4*)W1t,
                                               nW / 4, &sums[0], 1.0f / nW);
    ternarize_kernel<<<1024, 256, 0, stream>>>((const float4*)W2, (ushort4*)W2t,
                                               nW / 4, &sums[1], 1.0f / nW);
    cvt_bf16_kernel<<<2048, 256, 0, stream>>>((const float4*)x, (ushort4*)xb,
                                              (M * EMB) / 4);

    // GEMM1: h[M,FF] = gelu(x[M,EMB] * W1t[FF,EMB]^T + b1), bf16 out
    gemm_bt_kernel<0><<<dim3(FF / 128, M / 128), 256, 0, stream>>>(xb, W1t, b1, h, EMB, FF);
    // GEMM2: out[M,EMB] = h[M,FF] * W2t[EMB,FF]^T + b2, fp32 out
    gemm_bt_kernel<1><<<dim3(EMB / 128, M / 128), 256, 0, stream>>>(h, W2t, b2, out, FF, EMB);
}

// Round 2
// 299.942 us; speedup vs baseline: 1.2121x; 1.2121x over previous
//
#include <hip/hip_runtime.h>
#include <hip/hip_bf16.h>
#include <cstdint>
#include <cstddef>

typedef __bf16 bf16x8 __attribute__((ext_vector_type(8)));
typedef float  f32x4  __attribute__((ext_vector_type(4)));

__device__ __forceinline__ unsigned short f2bf(float f) {
    __hip_bfloat16 b = __float2bfloat16(f);
    return *reinterpret_cast<unsigned short*>(&b);
}

// ---------------- aux kernels ----------------

__global__ void zero2_kernel(float* p) {
    if (threadIdx.x < 2) p[threadIdx.x] = 0.0f;
}

// blocks [0,512) reduce w0 -> out[0]; blocks [512,1024) reduce w1 -> out[1]
__global__ void abs_sum2_kernel(const float4* __restrict__ w0, const float4* __restrict__ w1,
                                int n4, float* __restrict__ out) {
    int half = (int)blockIdx.x >> 9;               // 0 or 1
    const float4* w = half ? w1 : w0;
    int b = (int)blockIdx.x & 511;
    float s = 0.0f;
    for (int i = b * blockDim.x + threadIdx.x; i < n4; i += 512 * blockDim.x) {
        float4 v = w[i];
        s += fabsf(v.x) + fabsf(v.y) + fabsf(v.z) + fabsf(v.w);
    }
    #pragma unroll
    for (int o = 32; o > 0; o >>= 1) s += __shfl_down(s, o, 64);
    __shared__ float part[4];
    int lane = threadIdx.x & 63, wid = threadIdx.x >> 6;
    if (lane == 0) part[wid] = s;
    __syncthreads();
    if (threadIdx.x == 0) atomicAdd(&out[half], part[0] + part[1] + part[2] + part[3]);
}

// blocks [0,1024) ternarize w0 -> t0 with sum[0]; [1024,2048) w1 -> t1 with sum[1]
__global__ void ternarize2_kernel(const float4* __restrict__ w0, ushort4* __restrict__ t0,
                                  const float4* __restrict__ w1, ushort4* __restrict__ t1,
                                  int n4, const float* __restrict__ sum, float inv_n) {
    int half = (int)blockIdx.x >> 10;
    const float4* w = half ? w1 : w0;
    ushort4* t = half ? t1 : t0;
    int b = (int)blockIdx.x & 1023;
    float scale = fmaxf(sum[half] * inv_n, 1e-8f);
    float inv = 1.0f / scale;
    for (int i = b * blockDim.x + threadIdx.x; i < n4; i += 1024 * blockDim.x) {
        float4 v = w[i];
        ushort4 o;
        o.x = f2bf(fminf(fmaxf(rintf(v.x * inv), -1.0f), 1.0f));
        o.y = f2bf(fminf(fmaxf(rintf(v.y * inv), -1.0f), 1.0f));
        o.z = f2bf(fminf(fmaxf(rintf(v.z * inv), -1.0f), 1.0f));
        o.w = f2bf(fminf(fmaxf(rintf(v.w * inv), -1.0f), 1.0f));
        t[i] = o;
    }
}

__global__ void cvt_bf16_kernel(const float4* __restrict__ in, ushort4* __restrict__ out, int n4) {
    for (int i = blockIdx.x * blockDim.x + threadIdx.x; i < n4; i += gridDim.x * blockDim.x) {
        float4 v = in[i];
        ushort4 o;
        o.x = f2bf(v.x); o.y = f2bf(v.y); o.z = f2bf(v.z); o.w = f2bf(v.w);
        out[i] = o;
    }
}

// ---------------- GEMM (NT: C[m][n] = sum_k A[m][k]*B[n][k]) ----------------
// BM=BN=128, BK=64; 256 threads = 4 waves, each wave 64x64 via 4x4 of 16x16x32 MFMA.
// LDS layout XOR-swizzled in 16B chunks: logical (row, chunk cc) lives at
// physical chunk cc ^ (row&7). Implemented on the staging side by permuting the
// GLOBAL source column per lane (keeps global_load_lds's lane->LDS mapping and
// global coalescing: the 8 lanes of a row cover one contiguous 128B line).
// EPI==0: C = bf16 h, epilogue bias+exact GELU.  EPI==1: C = fp32 out, epilogue bias.

template <int EPI>
__global__ __launch_bounds__(256)
void gemm_bt_kernel(const unsigned short* __restrict__ A,
                    const unsigned short* __restrict__ B,
                    const float* __restrict__ bias,
                    void* __restrict__ C,
                    int K, int N) {
    __shared__ __align__(16) unsigned short As[128 * 64];
    __shared__ __align__(16) unsigned short Bs[128 * 64];

    const int tid  = threadIdx.x;
    const int lane = tid & 63;
    const int wid  = tid >> 6;
    const int wr   = wid >> 1;      // wave row 0..1
    const int wc   = wid & 1;       // wave col 0..1
    const int mBase = wr * 64;
    const int nBase = wc * 64;
    const int lr = lane & 15;       // 0..15
    const int lq = lane >> 4;       // quad 0..3

    const size_t aRow0 = (size_t)blockIdx.y * 128;
    const size_t bRow0 = (size_t)blockIdx.x * 128;

    f32x4 acc[4][4];
    #pragma unroll
    for (int i = 0; i < 4; ++i)
        #pragma unroll
        for (int j = 0; j < 4; ++j)
            acc[i][j] = f32x4{0.f, 0.f, 0.f, 0.f};

    for (int k0 = 0; k0 < K; k0 += 64) {
        __syncthreads();
        // stage 128x64 bf16 A-tile and B-tile via global_load_lds (16B/lane)
        #pragma unroll
        for (int t = 0; t < 4; ++t) {
            int chunk = t * 256 + tid;          // 0..1023, 8 bf16 per chunk
            int r = chunk >> 3;                 // row in tile
            int cc = chunk & 7;                 // physical 16B-chunk within row
            int c = ((cc ^ (r & 7)) << 3);      // swizzled logical column (bf16)
            const unsigned short* ga = A + (aRow0 + r) * (size_t)K + k0 + c;
            const unsigned short* gb = B + (bRow0 + r) * (size_t)K + k0 + c;
            __builtin_amdgcn_global_load_lds(
                (__attribute__((address_space(1))) void*)ga,
                (__attribute__((address_space(3))) void*)(&As[chunk * 8]), 16, 0, 0);
            __builtin_amdgcn_global_load_lds(
                (__attribute__((address_space(1))) void*)gb,
                (__attribute__((address_space(3))) void*)(&Bs[chunk * 8]), 16, 0, 0);
        }
        __syncthreads();
        // compute: 2 k-steps of 32
        #pragma unroll
        for (int ks = 0; ks < 2; ++ks) {
            // physical chunk for logical chunk (ks*4+lq) in a row with row&7 == lr&7
            const int swz = (((ks * 4 + lq) ^ (lr & 7)) << 3);
            bf16x8 avec[4], bvec[4];
            #pragma unroll
            for (int i = 0; i < 4; ++i) {
                avec[i] = *(const bf16x8*)&As[(mBase + i * 16 + lr) * 64 + swz];
                bvec[i] = *(const bf16x8*)&Bs[(nBase + i * 16 + lr) * 64 + swz];
            }
            #pragma unroll
            for (int mi = 0; mi < 4; ++mi)
                #pragma unroll
                for (int ni = 0; ni < 4; ++ni)
                    acc[mi][ni] = __builtin_amdgcn_mfma_f32_16x16x32_bf16(
                        avec[mi], bvec[ni], acc[mi][ni], 0, 0, 0);
        }
    }

    // epilogue. C/D layout: col = lane&15, row = (lane>>4)*4 + reg
    #pragma unroll
    for (int mi = 0; mi < 4; ++mi) {
        #pragma unroll
        for (int ni = 0; ni < 4; ++ni) {
            int col = (int)bRow0 + nBase + ni * 16 + lr;
            float bv = bias[col];
            #pragma unroll
            for (int r = 0; r < 4; ++r) {
                size_t row = aRow0 + mBase + mi * 16 + lq * 4 + r;
                float v = acc[mi][ni][r] + bv;
                if (EPI == 0) {
                    // exact GELU: 0.5*x*(1+erf(x/sqrt(2)))
                    v = 0.5f * v * (1.0f + erff(v * 0.70710678118f));
                    ((unsigned short*)C)[row * (size_t)N + col] = f2bf(v);
                } else {
                    ((float*)C)[row * (size_t)N + col] = v;
                }
            }
        }
    }
}

// ---------------- launch ----------------

extern "C" void kernel_launch(void* const* d_in, const int* in_sizes, int n_in,
                              void* d_out, int out_size, void* d_ws, size_t ws_size,
                              hipStream_t stream) {
    const float* x  = (const float*)d_in[0];   // [4,2048,1024] = 8388608
    const float* W1 = (const float*)d_in[1];   // [4096,1024]   = 4194304
    const float* b1 = (const float*)d_in[2];   // [4096]
    const float* W2 = (const float*)d_in[3];   // [1024,4096]   = 4194304
    const float* b2 = (const float*)d_in[4];   // [1024]
    float* out = (float*)d_out;                // fp32 [4,2048,1024]

    const int M = 8192, EMB = 1024, FF = 4096;
    const int nW = FF * EMB;                   // 4194304

    char* ws = (char*)d_ws;
    float* sums = (float*)ws;                                    // 2 floats
    unsigned short* W1t = (unsigned short*)(ws + 256);           // 8.39 MB
    unsigned short* W2t = W1t + (size_t)nW;                      // 8.39 MB
    unsigned short* xb  = W2t + (size_t)nW;                      // 16.78 MB
    unsigned short* h   = xb  + (size_t)M * EMB;                 // 67.1 MB

    zero2_kernel<<<1, 64, 0, stream>>>(sums);
    abs_sum2_kernel<<<1024, 256, 0, stream>>>((const float4*)W1, (const float4*)W2,
                                              nW / 4, sums);
    ternarize2_kernel<<<2048, 256, 0, stream>>>((const float4*)W1, (ushort4*)W1t,
                                                (const float4*)W2, (ushort4*)W2t,
                                                nW / 4, sums, 1.0f / nW);
    cvt_bf16_kernel<<<2048, 256, 0, stream>>>((const float4*)x, (ushort4*)xb,
                                              (M * EMB) / 4);

    // GEMM1: h[M,FF] = gelu(x[M,EMB] * W1t[FF,EMB]^T + b1), bf16 out
    gemm_bt_kernel<0><<<dim3(FF / 128, M / 128), 256, 0, stream>>>(xb, W1t, b1, h, EMB, FF);
    // GEMM2: out[M,EMB] = h[M,FF] * W2t[EMB,FF]^T + b2, fp32 out
    gemm_bt_kernel<1><<<dim3(EMB / 128, M / 128), 256, 0, stream>>>(h, W2t, b2, out, FF, EMB);
}

// Round 3
// 279.851 us; speedup vs baseline: 1.2992x; 1.0718x over previous
//
#include <hip/hip_runtime.h>
#include <hip/hip_bf16.h>
#include <cstdint>
#include <cstddef>

typedef __bf16 bf16x8 __attribute__((ext_vector_type(8)));
typedef float  f32x4  __attribute__((ext_vector_type(4)));

__device__ __forceinline__ unsigned short f2bf(float f) {
    __hip_bfloat16 b = __float2bfloat16(f);
    return *reinterpret_cast<unsigned short*>(&b);
}

// fast GELU (tanh form), ~7 VALU ops, saturation-safe:
// g = x / (1 + exp2(-2.8853900818 * (0.79788456x + 0.035677408x^3)))
__device__ __forceinline__ float fast_gelu(float x) {
    float x2 = x * x;
    float m  = x * __builtin_fmaf(x2, -0.10294314f, -2.30220795f);
    float e  = __builtin_amdgcn_exp2f(m);
    return x * __builtin_amdgcn_rcpf(1.0f + e);
}

// ---------------- aux kernels ----------------

__global__ void zero2_kernel(float* p) {
    if (threadIdx.x < 2) p[threadIdx.x] = 0.0f;
}

// blocks [0,512) reduce w0 -> out[0]; blocks [512,1024) reduce w1 -> out[1]
__global__ void abs_sum2_kernel(const float4* __restrict__ w0, const float4* __restrict__ w1,
                                int n4, float* __restrict__ out) {
    int half = (int)blockIdx.x >> 9;               // 0 or 1
    const float4* w = half ? w1 : w0;
    int b = (int)blockIdx.x & 511;
    float s = 0.0f;
    for (int i = b * blockDim.x + threadIdx.x; i < n4; i += 512 * blockDim.x) {
        float4 v = w[i];
        s += fabsf(v.x) + fabsf(v.y) + fabsf(v.z) + fabsf(v.w);
    }
    #pragma unroll
    for (int o = 32; o > 0; o >>= 1) s += __shfl_down(s, o, 64);
    __shared__ float part[4];
    int lane = threadIdx.x & 63, wid = threadIdx.x >> 6;
    if (lane == 0) part[wid] = s;
    __syncthreads();
    if (threadIdx.x == 0) atomicAdd(&out[half], part[0] + part[1] + part[2] + part[3]);
}

// blocks [0,1024): ternarize W1; [1024,2048): ternarize W2; [2048,3072): cvt x->bf16
__global__ void prep_kernel(const float4* __restrict__ w0, ushort4* __restrict__ t0,
                            const float4* __restrict__ w1, ushort4* __restrict__ t1,
                            int n4w,
                            const float4* __restrict__ x, ushort4* __restrict__ xb,
                            int n4x,
                            const float* __restrict__ sum, float inv_n) {
    int seg = (int)blockIdx.x >> 10;               // 0,1,2
    int b = (int)blockIdx.x & 1023;
    if (seg == 2) {
        for (int i = b * blockDim.x + threadIdx.x; i < n4x; i += 1024 * blockDim.x) {
            float4 v = x[i];
            ushort4 o;
            o.x = f2bf(v.x); o.y = f2bf(v.y); o.z = f2bf(v.z); o.w = f2bf(v.w);
            xb[i] = o;
        }
        return;
    }
    const float4* w = seg ? w1 : w0;
    ushort4* t = seg ? t1 : t0;
    float scale = fmaxf(sum[seg] * inv_n, 1e-8f);
    float inv = 1.0f / scale;
    for (int i = b * blockDim.x + threadIdx.x; i < n4w; i += 1024 * blockDim.x) {
        float4 v = w[i];
        ushort4 o;
        o.x = f2bf(fminf(fmaxf(rintf(v.x * inv), -1.0f), 1.0f));
        o.y = f2bf(fminf(fmaxf(rintf(v.y * inv), -1.0f), 1.0f));
        o.z = f2bf(fminf(fmaxf(rintf(v.z * inv), -1.0f), 1.0f));
        o.w = f2bf(fminf(fmaxf(rintf(v.w * inv), -1.0f), 1.0f));
        t[i] = o;
    }
}

// ---------------- GEMM (NT: C[m][n] = sum_k A[m][k]*B[n][k]) ----------------
// BM=BN=128, BK=64; 256 threads = 4 waves, each wave 64x64 via 4x4 of 16x16x32 MFMA.
// LDS XOR-swizzled in 16B chunks (physical chunk = logical ^ (row&7)), applied on
// the staging side by permuting the GLOBAL source column per lane.
// K, N are compile-time (powers of 2) so all index math is shifts and the
// staging pointers strength-reduce to += 64 elements per iteration.
// EPI==0: C = bf16, bias + fast GELU.  EPI==1: C = fp32, bias.

template <int EPI, int K, int N>
__global__ __launch_bounds__(256)
void gemm_bt_kernel(const unsigned short* __restrict__ A,
                    const unsigned short* __restrict__ B,
                    const float* __restrict__ bias,
                    void* __restrict__ C) {
    __shared__ __align__(16) unsigned short As[128 * 64];
    __shared__ __align__(16) unsigned short Bs[128 * 64];

    const int tid  = threadIdx.x;
    const int lane = tid & 63;
    const int wid  = tid >> 6;
    const int wr   = wid >> 1;      // wave row 0..1
    const int wc   = wid & 1;       // wave col 0..1
    const int mBase = wr * 64;
    const int nBase = wc * 64;
    const int lr = lane & 15;       // 0..15
    const int lq = lane >> 4;       // quad 0..3

    const size_t aRow0 = (size_t)blockIdx.y * 128;
    const size_t bRow0 = (size_t)blockIdx.x * 128;

    // staging pointers (hoisted; swizzle col is t-invariant since 32%8==0)
    const int rA  = tid >> 3;                       // 0..31
    const int cSw = (((tid & 7) ^ (rA & 7)) << 3);  // swizzled col in bf16 elems
    const unsigned short* ga = A + (aRow0 + rA) * (size_t)K + cSw;
    const unsigned short* gb = B + (bRow0 + rA) * (size_t)K + cSw;
    unsigned short* ldsA = &As[tid * 8];
    unsigned short* ldsB = &Bs[tid * 8];

    f32x4 acc[4][4];
    #pragma unroll
    for (int i = 0; i < 4; ++i)
        #pragma unroll
        for (int j = 0; j < 4; ++j)
            acc[i][j] = f32x4{0.f, 0.f, 0.f, 0.f};

    // LDS read offsets (loop-invariant)
    const int swz0 = ((lq ^ (lr & 7)) << 3);
    const int swz1 = (((4 + lq) ^ (lr & 7)) << 3);

    #pragma unroll 2
    for (int k0 = 0; k0 < K; k0 += 64) {
        __syncthreads();
        #pragma unroll
        for (int t = 0; t < 4; ++t) {
            __builtin_amdgcn_global_load_lds(
                (const __attribute__((address_space(1))) void*)(ga + (size_t)t * 32 * K),
                (__attribute__((address_space(3))) void*)(ldsA + t * 2048), 16, 0, 0);
            __builtin_amdgcn_global_load_lds(
                (const __attribute__((address_space(1))) void*)(gb + (size_t)t * 32 * K),
                (__attribute__((address_space(3))) void*)(ldsB + t * 2048), 16, 0, 0);
        }
        ga += 64;
        gb += 64;
        __syncthreads();
        #pragma unroll
        for (int ks = 0; ks < 2; ++ks) {
            const int swz = ks ? swz1 : swz0;
            bf16x8 avec[4], bvec[4];
            #pragma unroll
            for (int i = 0; i < 4; ++i) {
                avec[i] = *(const bf16x8*)&As[(mBase + i * 16 + lr) * 64 + swz];
                bvec[i] = *(const bf16x8*)&Bs[(nBase + i * 16 + lr) * 64 + swz];
            }
            #pragma unroll
            for (int mi = 0; mi < 4; ++mi)
                #pragma unroll
                for (int ni = 0; ni < 4; ++ni)
                    acc[mi][ni] = __builtin_amdgcn_mfma_f32_16x16x32_bf16(
                        avec[mi], bvec[ni], acc[mi][ni], 0, 0, 0);
        }
    }

    // epilogue. C/D layout: col = lane&15, row = (lane>>4)*4 + reg
    #pragma unroll
    for (int mi = 0; mi < 4; ++mi) {
        #pragma unroll
        for (int ni = 0; ni < 4; ++ni) {
            int col = (int)bRow0 + nBase + ni * 16 + lr;
            float bv = bias[col];
            #pragma unroll
            for (int r = 0; r < 4; ++r) {
                size_t row = aRow0 + mBase + mi * 16 + lq * 4 + r;
                float v = acc[mi][ni][r] + bv;
                if (EPI == 0) {
                    ((unsigned short*)C)[row * (size_t)N + col] = f2bf(fast_gelu(v));
                } else {
                    ((float*)C)[row * (size_t)N + col] = v;
                }
            }
        }
    }
}

// ---------------- launch ----------------

extern "C" void kernel_launch(void* const* d_in, const int* in_sizes, int n_in,
                              void* d_out, int out_size, void* d_ws, size_t ws_size,
                              hipStream_t stream) {
    const float* x  = (const float*)d_in[0];   // [4,2048,1024] = 8388608
    const float* W1 = (const float*)d_in[1];   // [4096,1024]   = 4194304
    const float* b1 = (const float*)d_in[2];   // [4096]
    const float* W2 = (const float*)d_in[3];   // [1024,4096]   = 4194304
    const float* b2 = (const float*)d_in[4];   // [1024]
    float* out = (float*)d_out;                // fp32 [4,2048,1024]

    const int M = 8192, EMB = 1024, FF = 4096;
    const int nW = FF * EMB;                   // 4194304

    char* ws = (char*)d_ws;
    float* sums = (float*)ws;                                    // 2 floats
    unsigned short* W1t = (unsigned short*)(ws + 256);           // 8.39 MB
    unsigned short* W2t = W1t + (size_t)nW;                      // 8.39 MB
    unsigned short* xb  = W2t + (size_t)nW;                      // 16.78 MB
    unsigned short* h   = xb  + (size_t)M * EMB;                 // 67.1 MB

    zero2_kernel<<<1, 64, 0, stream>>>(sums);
    abs_sum2_kernel<<<1024, 256, 0, stream>>>((const float4*)W1, (const float4*)W2,
                                              nW / 4, sums);
    prep_kernel<<<3072, 256, 0, stream>>>((const float4*)W1, (ushort4*)W1t,
                                          (const float4*)W2, (ushort4*)W2t, nW / 4,
                                          (const float4*)x, (ushort4*)xb, (M * EMB) / 4,
                                          sums, 1.0f / nW);

    // GEMM1: h[M,FF] = gelu(x[M,EMB] * W1t[FF,EMB]^T + b1), bf16 out
    gemm_bt_kernel<0, 1024, 4096><<<dim3(FF / 128, M / 128), 256, 0, stream>>>(xb, W1t, b1, h);
    // GEMM2: out[M,EMB] = h[M,FF] * W2t[EMB,FF]^T + b2, fp32 out
    gemm_bt_kernel<1, 4096, 1024><<<dim3(EMB / 128, M / 128), 256, 0, stream>>>(h, W2t, b2, out);
}